// Round 3
// baseline (481.316 us; speedup 1.0000x reference)
//
#include <hip/hip_runtime.h>
#include <cstdint>
#include <cstddef>

typedef __bf16 bf16;
typedef __bf16 bf16x4 __attribute__((ext_vector_type(4)));
typedef __bf16 bf16x8 __attribute__((ext_vector_type(8)));
typedef float  f32x4  __attribute__((ext_vector_type(4)));

#define MDIM 2048
#define NDIM 4096
#define KDIM 4096
#define FLOATMAX 3.402823466e38f

// ---------------- fp32 -> bf16 conversion (one launch for both tensors) ----------------
__global__ void cvt2_f32_to_bf16(const float* __restrict__ x, const float* __restrict__ w,
                                 bf16* __restrict__ xb, bf16* __restrict__ wb,
                                 int xn4, int wn4) {
    const int stride = gridDim.x * blockDim.x;
    int i = blockIdx.x * blockDim.x + threadIdx.x;
    for (int k = i; k < xn4; k += stride) {
        f32x4 v = reinterpret_cast<const f32x4*>(x)[k];
        reinterpret_cast<bf16x4*>(xb)[k] = __builtin_convertvector(v, bf16x4);
    }
    for (int k = i; k < wn4; k += stride) {
        f32x4 v = reinterpret_cast<const f32x4*>(w)[k];
        reinterpret_cast<bf16x4*>(wb)[k] = __builtin_convertvector(v, bf16x4);
    }
}

// async global->LDS, 16B per lane (HW: wave-uniform LDS base + lane*16)
__device__ __forceinline__ void g2lds16(const bf16* g, bf16* l) {
    __builtin_amdgcn_global_load_lds(
        (const __attribute__((address_space(1))) uint32_t*)g,
        (__attribute__((address_space(3))) uint32_t*)l, 16, 0, 0);
}

// ---------------- MAM main kernel ----------------
// Block tile 128(m) x 128(n); 256 threads = 4 waves in 2(m) x 2(n); wave tile 64x64.
// 64x64 raises LDS-read arithmetic intensity to 32 FLOP/byte (was 21 at 64x32):
// round-0 kernel was LDS-read-BW bound (MfmaUtil 20.7%, HBM 12%, conflicts 0).
// K: 64 stages of BK=64 (2 ACCBLOCKs each); SPLITS=2 handled sequentially:
// at stage 31 each thread stores its partial (mx+mn) to its own out elements
// (race-free, deterministic, idempotent across graph replays), resets mx/mn;
// epilogue adds stored + split1 + bias (same-thread RMW).
// This keeps only mx+mn (128 VGPRs) live in the K-loop -> fits 2 waves/EU.
// LDS double-buffered (64 KB): one barrier per stage, prefetch overlaps compute.
// Staging uses XOR chunk swizzle so fragment ds_read_b128 is 2-way conflict-free.
__global__ __launch_bounds__(256, 2) void mam_kernel(
    const bf16* __restrict__ A,   // [M,K] bf16 (x)
    const bf16* __restrict__ B,   // [N,K] bf16 (weight row n = col n of w)
    const float* __restrict__ bias,
    float* __restrict__ out)
{
    __shared__ __align__(16) bf16 sA[2][2][128 * 32];  // [parity][accblock-half]
    __shared__ __align__(16) bf16 sB[2][2][128 * 32];

    const int t    = threadIdx.x;
    const int lane = t & 63;
    const int w    = t >> 6;        // 0..3
    const int wm   = (w >> 1) * 64; // 0 or 64
    const int wn   = (w & 1) * 64;  // 0 or 64

    const int m0 = blockIdx.y * 128;
    const int n0 = blockIdx.x * 128;

    // staging: thread t -> row r = t>>2 (0..63; second row-block handled at +64),
    // slot p = t&3; fetches global chunk c = p ^ ((r>>1)&3).
    // ((r+64)>>1)&3 == (r>>1)&3 (64/2 = 32 == 0 mod 4), so the same chunk choice
    // is correct for both row-blocks.
    const int srow   = t >> 2;
    const int spos   = t & 3;
    const int schunk = spos ^ ((srow >> 1) & 3);
    const bf16* gA = A + (size_t)(m0 + srow) * KDIM + schunk * 8;
    const bf16* gB = B + (size_t)(n0 + srow) * KDIM + schunk * 8;
    const int ldst = t * 8;  // LDS dest: lane-contiguous 16B per 2048-elem region

    // fragment addressing: row R, chunk q=lane>>4 lives at slot q ^ ((R>>1)&3)
    const int frow = lane & 15;
    const int q    = lane >> 4;
    int offA[4], offB[4];
#pragma unroll
    for (int i = 0; i < 4; ++i) {
        const int Ra = wm + i * 16 + frow;
        offA[i] = Ra * 32 + (q ^ ((Ra >> 1) & 3)) * 8;
        const int Rb = wn + i * 16 + frow;
        offB[i] = Rb * 32 + (q ^ ((Rb >> 1) & 3)) * 8;
    }

    const f32x4 kZero = {0.f, 0.f, 0.f, 0.f};

    f32x4 mx[4][4], mn[4][4];
#pragma unroll
    for (int i = 0; i < 4; ++i)
#pragma unroll
        for (int j = 0; j < 4; ++j) {
            mx[i][j] = (f32x4)(-FLOATMAX);
            mn[i][j] = (f32x4)(FLOATMAX);
        }

    auto prefetch = [&](int s, int pb) {
        const bf16* ga = gA + (size_t)s * 64;
        const bf16* gb = gB + (size_t)s * 64;
        // [half][row-block]: row-block 1 = rows 64..127 -> +64*KDIM src, +2048 dst
        g2lds16(ga,                  &sA[pb][0][ldst]);
        g2lds16(ga + 64 * KDIM,      &sA[pb][0][2048 + ldst]);
        g2lds16(ga + 32,             &sA[pb][1][ldst]);
        g2lds16(ga + 64 * KDIM + 32, &sA[pb][1][2048 + ldst]);
        g2lds16(gb,                  &sB[pb][0][ldst]);
        g2lds16(gb + 64 * KDIM,      &sB[pb][0][2048 + ldst]);
        g2lds16(gb + 32,             &sB[pb][1][ldst]);
        g2lds16(gb + 64 * KDIM + 32, &sB[pb][1][2048 + ldst]);
    };

    auto compute = [&](int pb) {
        bf16x8 aF0[4], aF1[4], bF0[4], bF1[4];
#pragma unroll
        for (int i = 0; i < 4; ++i) {
            aF0[i] = *(const bf16x8*)&sA[pb][0][offA[i]];
            aF1[i] = *(const bf16x8*)&sA[pb][1][offA[i]];
            bF0[i] = *(const bf16x8*)&sB[pb][0][offB[i]];
            bF1[i] = *(const bf16x8*)&sB[pb][1][offB[i]];
        }
#pragma unroll
        for (int i = 0; i < 4; ++i) {
#pragma unroll
            for (int j = 0; j < 4; ++j) {
                f32x4 s0 = __builtin_amdgcn_mfma_f32_16x16x32_bf16(
                    aF0[i], bF0[j], kZero, 0, 0, 0);
                f32x4 s1 = __builtin_amdgcn_mfma_f32_16x16x32_bf16(
                    aF1[i], bF1[j], kZero, 0, 0, 0);
#pragma unroll
                for (int r = 0; r < 4; ++r) {
                    mx[i][j][r] = fmaxf(fmaxf(mx[i][j][r], s0[r]), s1[r]);  // v_max3_f32
                    mn[i][j][r] = fminf(fminf(mn[i][j][r], s0[r]), s1[r]);  // v_min3_f32
                }
            }
        }
    };

    // C/D layout: col=lane&15, row=(lane>>4)*4+reg
    const int orow = (lane >> 4) * 4;
    const int ocol = lane & 15;

    auto split_store_reset = [&]() {   // store split-0 partial to out, reset mx/mn
#pragma unroll
        for (int j = 0; j < 4; ++j) {
            const int col = n0 + wn + j * 16 + ocol;
#pragma unroll
            for (int i = 0; i < 4; ++i) {
                const int row = m0 + wm + i * 16 + orow;
#pragma unroll
                for (int r = 0; r < 4; ++r)
                    out[(size_t)(row + r) * NDIM + col] = mx[i][j][r] + mn[i][j][r];
                mx[i][j] = (f32x4)(-FLOATMAX);
                mn[i][j] = (f32x4)(FLOATMAX);
            }
        }
    };

    prefetch(0, 0);

    int bb = 0;
#pragma unroll 1
    for (int it = 0; it < 32; ++it) {
        // even stage: compute parity 0, prefetch into parity 1 (bb even <= 62 -> bb+1 valid)
        __syncthreads();
        prefetch(bb + 1, 1);
        compute(0);
        ++bb;
        // odd stage: compute parity 1, prefetch into parity 0
        __syncthreads();
        if (bb < 63) prefetch(bb + 1, 0);
        compute(1);
        if (bb == 31) split_store_reset();   // end of split 0 (k 0..2047)
        ++bb;
    }

    // epilogue: out = split0(stored) + split1(mx+mn) + bias; same-thread RMW, race-free
#pragma unroll
    for (int j = 0; j < 4; ++j) {
        const int col = n0 + wn + j * 16 + ocol;
        const float bv = bias[col];
#pragma unroll
        for (int i = 0; i < 4; ++i) {
            const int row = m0 + wm + i * 16 + orow;
#pragma unroll
            for (int r = 0; r < 4; ++r) {
                const size_t idx = (size_t)(row + r) * NDIM + col;
                out[idx] = out[idx] + (mx[i][j][r] + mn[i][j][r]) + bv;
            }
        }
    }
}

extern "C" void kernel_launch(void* const* d_in, const int* in_sizes, int n_in,
                              void* d_out, int out_size, void* d_ws, size_t ws_size,
                              hipStream_t stream) {
    const float* x    = (const float*)d_in[0];  // [M,K]
    const float* wgt  = (const float*)d_in[1];  // [N,K]
    const float* bias = (const float*)d_in[2];  // [N]
    float* out = (float*)d_out;

    bf16* xbf = (bf16*)d_ws;                        // M*K bf16 = 16 MiB
    bf16* wbf = xbf + (size_t)MDIM * KDIM;          // N*K bf16 = 32 MiB

    const int xn4 = (MDIM * KDIM) / 4;
    const int wn4 = (NDIM * KDIM) / 4;
    cvt2_f32_to_bf16<<<dim3(4096), dim3(256), 0, stream>>>(x, wgt, xbf, wbf, xn4, wn4);

    dim3 grid(NDIM / 128, MDIM / 128);  // (32, 16)
    mam_kernel<<<grid, dim3(256), 0, stream>>>(xbf, wbf, bias, out);
}

// Round 4
// 341.557 us; speedup vs baseline: 1.4092x; 1.4092x over previous
//
#include <hip/hip_runtime.h>
#include <cstdint>
#include <cstddef>

typedef __bf16 bf16;
typedef __bf16 bf16x4 __attribute__((ext_vector_type(4)));
typedef __bf16 bf16x8 __attribute__((ext_vector_type(8)));
typedef float  f32x4  __attribute__((ext_vector_type(4)));

#define MDIM 2048
#define NDIM 4096
#define KDIM 4096
#define FLOATMAX 3.402823466e38f

// ---------------- fp32 -> bf16 conversion (one launch for both tensors) ----------------
__global__ void cvt2_f32_to_bf16(const float* __restrict__ x, const float* __restrict__ w,
                                 bf16* __restrict__ xb, bf16* __restrict__ wb,
                                 int xn4, int wn4) {
    const int stride = gridDim.x * blockDim.x;
    int i = blockIdx.x * blockDim.x + threadIdx.x;
    for (int k = i; k < xn4; k += stride) {
        f32x4 v = reinterpret_cast<const f32x4*>(x)[k];
        reinterpret_cast<bf16x4*>(xb)[k] = __builtin_convertvector(v, bf16x4);
    }
    for (int k = i; k < wn4; k += stride) {
        f32x4 v = reinterpret_cast<const f32x4*>(w)[k];
        reinterpret_cast<bf16x4*>(wb)[k] = __builtin_convertvector(v, bf16x4);
    }
}

// async global->LDS, 16B per lane (HW: wave-uniform LDS base + lane*16)
__device__ __forceinline__ void g2lds16(const bf16* g, bf16* l) {
    __builtin_amdgcn_global_load_lds(
        (const __attribute__((address_space(1))) uint32_t*)g,
        (__attribute__((address_space(3))) uint32_t*)l, 16, 0, 0);
}

// ---------------- MAM main kernel ----------------
// Block tile 128(m) x 128(n); 256 threads = 4 waves in 2(m) x 2(n); wave tile 64x64.
// 64x64 gives 32 FLOP per LDS byte (vs 21 at 64x32) and, at 256 threads, 2 blocks/CU
// (R0's 512-thread version was register-limited to 1 block/CU -> barrier drains had
// nothing to overlap with; occupancy 21.8%).
// REGISTER BUDGET (the R3 lesson): gfx950 VGPR+AGPR are one file, ~512 regs/SIMD;
// launch_bounds(256,2) caps combined usage at 256/wave. mx+mn = 128 (AGPR).
// R3 loaded all 16 fragments up-front (+64) and spilled (WRITE_SIZE 484 MB of
// scratch thrash, 370 us). Fix: keep only B-fragments resident (8 x bf16x8 = 32),
// STREAM A-fragments one (a0,a1) pair per i (8 regs). Peak live ~205 < 256.
// K: 64 stages of BK=64 (2 ACCBLOCKs each); SPLITS=2 handled sequentially:
// at stage 31 each thread stores its partial (mx+mn) to its own out elements
// (race-free, deterministic, idempotent across graph replays), resets mx/mn;
// epilogue adds stored + split1 + bias (same-thread RMW).
// LDS double-buffered (64 KB): one barrier per stage, prefetch overlaps compute.
// Staging uses XOR chunk swizzle so fragment ds_read_b128 is 2-way conflict-free.
__global__ __launch_bounds__(256, 2) void mam_kernel(
    const bf16* __restrict__ A,   // [M,K] bf16 (x)
    const bf16* __restrict__ B,   // [N,K] bf16 (weight row n = col n of w)
    const float* __restrict__ bias,
    float* __restrict__ out)
{
    __shared__ __align__(16) bf16 sA[2][2][128 * 32];  // [parity][accblock-half]
    __shared__ __align__(16) bf16 sB[2][2][128 * 32];

    const int t    = threadIdx.x;
    const int lane = t & 63;
    const int w    = t >> 6;        // 0..3
    const int wm   = (w >> 1) * 64; // 0 or 64
    const int wn   = (w & 1) * 64;  // 0 or 64

    const int m0 = blockIdx.y * 128;
    const int n0 = blockIdx.x * 128;

    // staging: thread t -> row r = t>>2 (0..63; second row-block handled at +64),
    // slot p = t&3; fetches global chunk c = p ^ ((r>>1)&3).
    // ((r+64)>>1)&3 == (r>>1)&3 (64/2 = 32 == 0 mod 4), so the same chunk choice
    // is correct for both row-blocks.
    const int srow   = t >> 2;
    const int spos   = t & 3;
    const int schunk = spos ^ ((srow >> 1) & 3);
    const bf16* gA = A + (size_t)(m0 + srow) * KDIM + schunk * 8;
    const bf16* gB = B + (size_t)(n0 + srow) * KDIM + schunk * 8;
    const int ldst = t * 8;  // LDS dest: lane-contiguous 16B per 2048-elem region

    // fragment addressing: row R, chunk q=lane>>4 lives at slot q ^ ((R>>1)&3)
    const int frow = lane & 15;
    const int q    = lane >> 4;
    int offA[4], offB[4];
#pragma unroll
    for (int i = 0; i < 4; ++i) {
        const int Ra = wm + i * 16 + frow;
        offA[i] = Ra * 32 + (q ^ ((Ra >> 1) & 3)) * 8;
        const int Rb = wn + i * 16 + frow;
        offB[i] = Rb * 32 + (q ^ ((Rb >> 1) & 3)) * 8;
    }

    const f32x4 kZero = {0.f, 0.f, 0.f, 0.f};

    f32x4 mx[4][4], mn[4][4];
#pragma unroll
    for (int i = 0; i < 4; ++i)
#pragma unroll
        for (int j = 0; j < 4; ++j) {
            mx[i][j] = (f32x4)(-FLOATMAX);
            mn[i][j] = (f32x4)(FLOATMAX);
        }

    auto prefetch = [&](int s, int pb) {
        const bf16* ga = gA + (size_t)s * 64;
        const bf16* gb = gB + (size_t)s * 64;
        // [half][row-block]: row-block 1 = rows 64..127 -> +64*KDIM src, +2048 dst
        g2lds16(ga,                  &sA[pb][0][ldst]);
        g2lds16(ga + 64 * KDIM,      &sA[pb][0][2048 + ldst]);
        g2lds16(ga + 32,             &sA[pb][1][ldst]);
        g2lds16(ga + 64 * KDIM + 32, &sA[pb][1][2048 + ldst]);
        g2lds16(gb,                  &sB[pb][0][ldst]);
        g2lds16(gb + 64 * KDIM,      &sB[pb][0][2048 + ldst]);
        g2lds16(gb + 32,             &sB[pb][1][ldst]);
        g2lds16(gb + 64 * KDIM + 32, &sB[pb][1][2048 + ldst]);
    };

    auto compute = [&](int pb) {
        // B-fragments resident for the whole stage (8 x bf16x8 = 32 VGPRs)
        bf16x8 bF0[4], bF1[4];
#pragma unroll
        for (int j = 0; j < 4; ++j) {
            bF0[j] = *(const bf16x8*)&sB[pb][0][offB[j]];
            bF1[j] = *(const bf16x8*)&sB[pb][1][offB[j]];
        }
        // stream A-fragments: one (a0,a1) pair live at a time (8 VGPRs)
#pragma unroll
        for (int i = 0; i < 4; ++i) {
            const bf16x8 a0 = *(const bf16x8*)&sA[pb][0][offA[i]];
            const bf16x8 a1 = *(const bf16x8*)&sA[pb][1][offA[i]];
#pragma unroll
            for (int j = 0; j < 4; ++j) {
                f32x4 s0 = __builtin_amdgcn_mfma_f32_16x16x32_bf16(
                    a0, bF0[j], kZero, 0, 0, 0);
                f32x4 s1 = __builtin_amdgcn_mfma_f32_16x16x32_bf16(
                    a1, bF1[j], kZero, 0, 0, 0);
#pragma unroll
                for (int r = 0; r < 4; ++r) {
                    mx[i][j][r] = fmaxf(fmaxf(mx[i][j][r], s0[r]), s1[r]);  // v_max3_f32
                    mn[i][j][r] = fminf(fminf(mn[i][j][r], s0[r]), s1[r]);  // v_min3_f32
                }
            }
        }
    };

    // C/D layout: col=lane&15, row=(lane>>4)*4+reg
    const int orow = (lane >> 4) * 4;
    const int ocol = lane & 15;

    auto split_store_reset = [&]() {   // store split-0 partial to out, reset mx/mn
#pragma unroll
        for (int j = 0; j < 4; ++j) {
            const int col = n0 + wn + j * 16 + ocol;
#pragma unroll
            for (int i = 0; i < 4; ++i) {
                const int row = m0 + wm + i * 16 + orow;
#pragma unroll
                for (int r = 0; r < 4; ++r)
                    out[(size_t)(row + r) * NDIM + col] = mx[i][j][r] + mn[i][j][r];
                mx[i][j] = (f32x4)(-FLOATMAX);
                mn[i][j] = (f32x4)(FLOATMAX);
            }
        }
    };

    prefetch(0, 0);

    int bb = 0;
#pragma unroll 1
    for (int it = 0; it < 32; ++it) {
        // even stage: compute parity 0, prefetch into parity 1 (bb even <= 62 -> bb+1 valid)
        __syncthreads();
        prefetch(bb + 1, 1);
        compute(0);
        ++bb;
        // odd stage: compute parity 1, prefetch into parity 0
        __syncthreads();
        if (bb < 63) prefetch(bb + 1, 0);
        compute(1);
        if (bb == 31) split_store_reset();   // end of split 0 (k 0..2047)
        ++bb;
    }

    // epilogue: out = split0(stored) + split1(mx+mn) + bias; same-thread RMW, race-free
#pragma unroll
    for (int j = 0; j < 4; ++j) {
        const int col = n0 + wn + j * 16 + ocol;
        const float bv = bias[col];
#pragma unroll
        for (int i = 0; i < 4; ++i) {
            const int row = m0 + wm + i * 16 + orow;
#pragma unroll
            for (int r = 0; r < 4; ++r) {
                const size_t idx = (size_t)(row + r) * NDIM + col;
                out[idx] = out[idx] + (mx[i][j][r] + mn[i][j][r]) + bv;
            }
        }
    }
}

extern "C" void kernel_launch(void* const* d_in, const int* in_sizes, int n_in,
                              void* d_out, int out_size, void* d_ws, size_t ws_size,
                              hipStream_t stream) {
    const float* x    = (const float*)d_in[0];  // [M,K]
    const float* wgt  = (const float*)d_in[1];  // [N,K]
    const float* bias = (const float*)d_in[2];  // [N]
    float* out = (float*)d_out;

    bf16* xbf = (bf16*)d_ws;                        // M*K bf16 = 16 MiB
    bf16* wbf = xbf + (size_t)MDIM * KDIM;          // N*K bf16 = 32 MiB

    const int xn4 = (MDIM * KDIM) / 4;
    const int wn4 = (NDIM * KDIM) / 4;
    cvt2_f32_to_bf16<<<dim3(4096), dim3(256), 0, stream>>>(x, wgt, xbf, wbf, xn4, wn4);

    dim3 grid(NDIM / 128, MDIM / 128);  // (32, 16)
    mam_kernel<<<grid, dim3(256), 0, stream>>>(xbf, wbf, bias, out);
}

// Round 5
// 317.423 us; speedup vs baseline: 1.5163x; 1.0760x over previous
//
#include <hip/hip_runtime.h>
#include <cstdint>
#include <cstddef>

typedef __bf16 bf16;
typedef __bf16 bf16x4 __attribute__((ext_vector_type(4)));
typedef __bf16 bf16x8 __attribute__((ext_vector_type(8)));
typedef float  f32x4  __attribute__((ext_vector_type(4)));

#define MDIM 2048
#define NDIM 4096
#define KDIM 4096
#define FLOATMAX 3.402823466e38f

// ---------------- fp32 -> bf16 conversion (one launch for both tensors) ----------------
__global__ void cvt2_f32_to_bf16(const float* __restrict__ x, const float* __restrict__ w,
                                 bf16* __restrict__ xb, bf16* __restrict__ wb,
                                 int xn4, int wn4) {
    const int stride = gridDim.x * blockDim.x;
    int i = blockIdx.x * blockDim.x + threadIdx.x;
    for (int k = i; k < xn4; k += stride) {
        f32x4 v = reinterpret_cast<const f32x4*>(x)[k];
        reinterpret_cast<bf16x4*>(xb)[k] = __builtin_convertvector(v, bf16x4);
    }
    for (int k = i; k < wn4; k += stride) {
        f32x4 v = reinterpret_cast<const f32x4*>(w)[k];
        reinterpret_cast<bf16x4*>(wb)[k] = __builtin_convertvector(v, bf16x4);
    }
}

// async global->LDS, 16B per lane (HW: wave-uniform LDS base + lane*16)
__device__ __forceinline__ void g2lds16(const bf16* g, bf16* l) {
    __builtin_amdgcn_global_load_lds(
        (const __attribute__((address_space(1))) uint32_t*)g,
        (__attribute__((address_space(3))) uint32_t*)l, 16, 0, 0);
}

// ---------------- MAM main kernel ----------------
// Block tile 128(m) x 128(n); 256 threads = 4 waves in 2(m) x 2(n); wave tile 64x64
// (32 FLOP per LDS byte; LDS-read floor ~41 us).
// REGISTER DISCIPLINE (R3/R4 lessons): launch_bounds(256,2) caps VGPR+AGPR at 256.
// mx+mn = 128; B-frags resident = 32; A-frags must be STREAMED. R4 streamed them in
// source, but the scheduler hoisted all ds_reads back to the region top and spilled
// ~5 regs/stage (WRITE_SIZE 220 MB vs 66 expected). Fix: sched_barrier(0) at the end
// of each i-iteration makes 4 scheduling regions per stage -> at most one (a0,a1)
// pair + one region's MFMA temps live (~225 regs total demand < 256).
// split_store_reset hoisted out of the K-loop (two 16-iter loops) to keep the
// store-addressing out of loop liveness.
// K: 64 stages of BK=64 (2 ACCBLOCKs each); SPLITS=2 sequential: after stage 31
// store partial (mx+mn) to out (race-free, idempotent), reset; epilogue adds
// stored + split1 + bias (same-thread RMW).
// LDS double-buffered (64 KB): one barrier per stage, prefetch overlaps compute.
// Staging uses XOR chunk swizzle so fragment ds_read_b128 is 2-way conflict-free.
__global__ __launch_bounds__(256, 2) void mam_kernel(
    const bf16* __restrict__ A,   // [M,K] bf16 (x)
    const bf16* __restrict__ B,   // [N,K] bf16 (weight row n = col n of w)
    const float* __restrict__ bias,
    float* __restrict__ out)
{
    __shared__ __align__(16) bf16 sA[2][2][128 * 32];  // [parity][accblock-half]
    __shared__ __align__(16) bf16 sB[2][2][128 * 32];

    const int t    = threadIdx.x;
    const int lane = t & 63;
    const int w    = t >> 6;        // 0..3
    const int wm   = (w >> 1) * 64; // 0 or 64
    const int wn   = (w & 1) * 64;  // 0 or 64

    const int m0 = blockIdx.y * 128;
    const int n0 = blockIdx.x * 128;

    // staging: thread t -> row r = t>>2 (0..63; second row-block handled at +64),
    // slot p = t&3; fetches global chunk c = p ^ ((r>>1)&3).
    // ((r+64)>>1)&3 == (r>>1)&3, so the same chunk choice serves both row-blocks.
    const int srow   = t >> 2;
    const int spos   = t & 3;
    const int schunk = spos ^ ((srow >> 1) & 3);
    const bf16* gA = A + (size_t)(m0 + srow) * KDIM + schunk * 8;
    const bf16* gB = B + (size_t)(n0 + srow) * KDIM + schunk * 8;
    const int ldst = t * 8;  // LDS dest: lane-contiguous 16B per 2048-elem region

    // fragment addressing: row R, chunk q=lane>>4 lives at slot q ^ ((R>>1)&3)
    const int frow = lane & 15;
    const int q    = lane >> 4;
    int offA[4], offB[4];
#pragma unroll
    for (int i = 0; i < 4; ++i) {
        const int Ra = wm + i * 16 + frow;
        offA[i] = Ra * 32 + (q ^ ((Ra >> 1) & 3)) * 8;
        const int Rb = wn + i * 16 + frow;
        offB[i] = Rb * 32 + (q ^ ((Rb >> 1) & 3)) * 8;
    }

    const f32x4 kZero = {0.f, 0.f, 0.f, 0.f};

    f32x4 mx[4][4], mn[4][4];
#pragma unroll
    for (int i = 0; i < 4; ++i)
#pragma unroll
        for (int j = 0; j < 4; ++j) {
            mx[i][j] = (f32x4)(-FLOATMAX);
            mn[i][j] = (f32x4)(FLOATMAX);
        }

    auto prefetch = [&](int s, int pb) {
        const bf16* ga = gA + (size_t)s * 64;
        const bf16* gb = gB + (size_t)s * 64;
        // [half][row-block]: row-block 1 = rows 64..127 -> +64*KDIM src, +2048 dst
        g2lds16(ga,                  &sA[pb][0][ldst]);
        g2lds16(ga + 64 * KDIM,      &sA[pb][0][2048 + ldst]);
        g2lds16(ga + 32,             &sA[pb][1][ldst]);
        g2lds16(ga + 64 * KDIM + 32, &sA[pb][1][2048 + ldst]);
        g2lds16(gb,                  &sB[pb][0][ldst]);
        g2lds16(gb + 64 * KDIM,      &sB[pb][0][2048 + ldst]);
        g2lds16(gb + 32,             &sB[pb][1][ldst]);
        g2lds16(gb + 64 * KDIM + 32, &sB[pb][1][2048 + ldst]);
    };

    auto compute = [&](int pb) {
        // B-fragments resident for the whole stage (8 x bf16x8 = 32 VGPRs)
        bf16x8 bF0[4], bF1[4];
#pragma unroll
        for (int j = 0; j < 4; ++j) {
            bF0[j] = *(const bf16x8*)&sB[pb][0][offB[j]];
            bF1[j] = *(const bf16x8*)&sB[pb][1][offB[j]];
        }
        // stream A-fragments: sched_barrier(0) pins one (a0,a1) pair per region,
        // preventing the scheduler from hoisting all 8 A-loads (the R4 spill cause).
#pragma unroll
        for (int i = 0; i < 4; ++i) {
            const bf16x8 a0 = *(const bf16x8*)&sA[pb][0][offA[i]];
            const bf16x8 a1 = *(const bf16x8*)&sA[pb][1][offA[i]];
#pragma unroll
            for (int j = 0; j < 4; ++j) {
                f32x4 s0 = __builtin_amdgcn_mfma_f32_16x16x32_bf16(
                    a0, bF0[j], kZero, 0, 0, 0);
                f32x4 s1 = __builtin_amdgcn_mfma_f32_16x16x32_bf16(
                    a1, bF1[j], kZero, 0, 0, 0);
#pragma unroll
                for (int r = 0; r < 4; ++r) {
                    mx[i][j][r] = fmaxf(fmaxf(mx[i][j][r], s0[r]), s1[r]);  // v_max3_f32
                    mn[i][j][r] = fminf(fminf(mn[i][j][r], s0[r]), s1[r]);  // v_min3_f32
                }
            }
            __builtin_amdgcn_sched_barrier(0);
        }
    };

    // C/D layout: col=lane&15, row=(lane>>4)*4+reg
    const int orow = (lane >> 4) * 4;
    const int ocol = lane & 15;

    prefetch(0, 0);

    int bb = 0;
    // ---- split 0: stages 0..31 ----
#pragma unroll 1
    for (int it = 0; it < 16; ++it) {
        __syncthreads();
        prefetch(bb + 1, 1);   // bb even <= 30 -> bb+1 <= 31
        compute(0);
        ++bb;
        __syncthreads();
        prefetch(bb + 1, 0);   // bb odd <= 31 -> bb+1 <= 32 (stage 32, parity 0)
        compute(1);
        ++bb;
    }

    // store split-0 partial to out (race-free, idempotent), reset mx/mn
#pragma unroll
    for (int j = 0; j < 4; ++j) {
        const int col = n0 + wn + j * 16 + ocol;
#pragma unroll
        for (int i = 0; i < 4; ++i) {
            const int row = m0 + wm + i * 16 + orow;
#pragma unroll
            for (int r = 0; r < 4; ++r)
                out[(size_t)(row + r) * NDIM + col] = mx[i][j][r] + mn[i][j][r];
            mx[i][j] = (f32x4)(-FLOATMAX);
            mn[i][j] = (f32x4)(FLOATMAX);
        }
    }

    // ---- split 1: stages 32..63 ----
#pragma unroll 1
    for (int it = 0; it < 16; ++it) {
        __syncthreads();
        prefetch(bb + 1, 1);   // bb=32 -> prefetch 33 into parity 1
        compute(0);
        ++bb;
        __syncthreads();
        if (bb < 63) prefetch(bb + 1, 0);
        compute(1);
        ++bb;
    }

    // epilogue: out = split0(stored) + split1(mx+mn) + bias; same-thread RMW, race-free
#pragma unroll
    for (int j = 0; j < 4; ++j) {
        const int col = n0 + wn + j * 16 + ocol;
        const float bv = bias[col];
#pragma unroll
        for (int i = 0; i < 4; ++i) {
            const int row = m0 + wm + i * 16 + orow;
#pragma unroll
            for (int r = 0; r < 4; ++r) {
                const size_t idx = (size_t)(row + r) * NDIM + col;
                out[idx] = out[idx] + (mx[i][j][r] + mn[i][j][r]) + bv;
            }
        }
    }
}

extern "C" void kernel_launch(void* const* d_in, const int* in_sizes, int n_in,
                              void* d_out, int out_size, void* d_ws, size_t ws_size,
                              hipStream_t stream) {
    const float* x    = (const float*)d_in[0];  // [M,K]
    const float* wgt  = (const float*)d_in[1];  // [N,K]
    const float* bias = (const float*)d_in[2];  // [N]
    float* out = (float*)d_out;

    bf16* xbf = (bf16*)d_ws;                        // M*K bf16 = 16 MiB
    bf16* wbf = xbf + (size_t)MDIM * KDIM;          // N*K bf16 = 32 MiB

    const int xn4 = (MDIM * KDIM) / 4;
    const int wn4 = (NDIM * KDIM) / 4;
    cvt2_f32_to_bf16<<<dim3(4096), dim3(256), 0, stream>>>(x, wgt, xbf, wbf, xn4, wn4);

    dim3 grid(NDIM / 128, MDIM / 128);  // (32, 16)
    mam_kernel<<<grid, dim3(256), 0, stream>>>(xbf, wbf, bias, out);
}